// Round 2
// baseline (301.157 us; speedup 1.0000x reference)
//
#include <hip/hip_runtime.h>

// y[rows[k]] += vals[k] * x[cols[k]]  — M=N=262144, NNZ=8388608, out 512x512 f32.
// Pipeline: init (zero y + cursors) -> direct LDS bucket scatter (1 atomic/entry,
// 16 entries/thread ILP) into 32 row-bins -> fused per-bin-slice LDS accumulation
// with atomic dump straight into y (no partials, no reduce kernel).

#define BINS         32
#define ROW_SHIFT    13            // 8192 rows per bin
#define ROWS_PER_BIN 8192
#define ENT          4096          // entries per scatter block (16/thread)
#define BKT_CAP      200           // LDS bucket capacity: mean 128, sigma 11.1 -> 6.5 sigma
#define KST          202           // key bucket stride (u16): 404B -> rotates banks
#define VST          201           // val bucket stride (f32): 804B -> rotates banks
#define CUR_STRIDE   32            // global cursor padding: 1 counter per 128B line
#define OVF_SLOT     (BINS * CUR_STRIDE)
#define OVF_CAP      65536
#define SLICES       16

typedef int   __attribute__((ext_vector_type(4))) i32x4;
typedef float __attribute__((ext_vector_type(4))) f32x4;

// ---------------- fallback path (known-correct) ----------------

__global__ __launch_bounds__(256) void zero_out_kernel(float* __restrict__ y, int n) {
    int i = blockIdx.x * blockDim.x + threadIdx.x;
    if (i < n) y[i] = 0.0f;
}

__global__ __launch_bounds__(256) void spmv_coo_scatter(
    const float* __restrict__ vals, const int* __restrict__ rows,
    const int* __restrict__ cols, const float* __restrict__ x,
    float* __restrict__ y, int nnz)
{
    int i = (blockIdx.x * blockDim.x + threadIdx.x) * 4;
    if (i + 3 < nnz) {
        float4 v = *reinterpret_cast<const float4*>(vals + i);
        int4   r = *reinterpret_cast<const int4*>(rows + i);
        int4   c = *reinterpret_cast<const int4*>(cols + i);
        atomicAdd(&y[r.x], v.x * x[c.x]);
        atomicAdd(&y[r.y], v.y * x[c.y]);
        atomicAdd(&y[r.z], v.z * x[c.z]);
        atomicAdd(&y[r.w], v.w * x[c.w]);
    } else {
        for (; i < nnz; ++i) atomicAdd(&y[rows[i]], vals[i] * x[cols[i]]);
    }
}

// ---------------- binned path ----------------

// Zero y and the cursor block in one launch.
__global__ __launch_bounds__(256) void init_kernel(
    float* __restrict__ y, int n, unsigned* __restrict__ gcur, int ncur)
{
    int i = blockIdx.x * 256 + threadIdx.x;
    if (i < n) y[i] = 0.0f;
    if (i < ncur) gcur[i] = 0u;
}

// Direct LDS bucket scatter: single atomic cursor bump per entry, 16 entries per
// thread for gather ILP, then per-wave coalesced copy-out per bucket.
__global__ __launch_bounds__(256) void scatter_bucket_kernel(
    const int*   __restrict__ rows, const int* __restrict__ cols,
    const float* __restrict__ vals, const float* __restrict__ x, int nnz,
    unsigned* __restrict__ gcur, unsigned cap,
    unsigned short* __restrict__ okeys, float* __restrict__ ocontrib,
    uint2* __restrict__ ovf)
{
    __shared__ unsigned short skey[BINS * KST];   // 12928 B
    __shared__ float          sval[BINS * VST];   // 25728 B
    __shared__ unsigned cur[BINS];
    __shared__ unsigned scnt[BINS];
    __shared__ unsigned resv[BINS];

    const int t = threadIdx.x;
    if (t < BINS) cur[t] = 0u;
    __syncthreads();

    const int seg = blockIdx.x * ENT;

    int   rr[16];
    float ff[16];

    // Load triplets (non-temporal stream), compute contribs. All 16 gathers of
    // x[col] are independent -> deep MLP per thread.
    #pragma unroll
    for (int ch = 0; ch < 4; ++ch) {
        int base = seg + ch * 1024 + t * 4;
        if (base + 3 < nnz) {
            i32x4 r4 = __builtin_nontemporal_load(reinterpret_cast<const i32x4*>(rows + base));
            i32x4 c4 = __builtin_nontemporal_load(reinterpret_cast<const i32x4*>(cols + base));
            f32x4 v4 = __builtin_nontemporal_load(reinterpret_cast<const f32x4*>(vals + base));
            rr[ch*4+0] = r4.x; ff[ch*4+0] = v4.x * x[c4.x];
            rr[ch*4+1] = r4.y; ff[ch*4+1] = v4.y * x[c4.y];
            rr[ch*4+2] = r4.z; ff[ch*4+2] = v4.z * x[c4.z];
            rr[ch*4+3] = r4.w; ff[ch*4+3] = v4.w * x[c4.w];
        } else {
            #pragma unroll
            for (int j = 0; j < 4; ++j) {
                int idx = base + j;
                if (idx < nnz) { rr[ch*4+j] = rows[idx]; ff[ch*4+j] = vals[idx] * x[cols[idx]]; }
                else           { rr[ch*4+j] = -1; ff[ch*4+j] = 0.0f; }
            }
        }
    }

    // Place: one LDS atomic per entry; rare overflow spills to global list.
    #pragma unroll
    for (int j = 0; j < 16; ++j) {
        if (rr[j] >= 0) {
            int b = rr[j] >> ROW_SHIFT;
            unsigned p = atomicAdd(&cur[b], 1u);
            if (p < BKT_CAP) {
                skey[b * KST + p] = (unsigned short)(rr[j] & (ROWS_PER_BIN - 1));
                sval[b * VST + p] = ff[j];
            } else {
                unsigned q = atomicAdd(&gcur[OVF_SLOT], 1u);
                if (q < OVF_CAP) ovf[q] = make_uint2((unsigned)rr[j], __float_as_uint(ff[j]));
            }
        }
    }
    __syncthreads();

    // Reserve global space per bin (padded cursors: 32 independent cache lines).
    if (t < BINS) {
        unsigned c = cur[t]; if (c > BKT_CAP) c = BKT_CAP;
        scnt[t] = c;
        resv[t] = atomicAdd(&gcur[t * CUR_STRIDE], c);
    }
    __syncthreads();

    // Copy-out: wave w owns buckets [8w, 8w+8); coalesced within each bucket run.
    const int wave = t >> 6, lane = t & 63;
    #pragma unroll
    for (int k = 0; k < BINS / 4; ++k) {
        int b = wave * (BINS / 4) + k;
        unsigned cnt  = scnt[b];
        unsigned base = resv[b];
        const size_t binoff = (size_t)b * cap;
        for (unsigned i = lane; i < cnt; i += 64) {
            unsigned off = base + i;
            if (off < cap) {
                okeys[binoff + off]    = skey[b * KST + i];
                ocontrib[binoff + off] = sval[b * VST + i];
            }
        }
    }
}

// Fused accumulate + output: one block per (bin, slice). Accumulate slice entries
// into a 32KB LDS slab, then atomicAdd the slab straight into y (coalesced).
// Replaces partials round-trip (67MB) + reduce kernel.
__global__ __launch_bounds__(512) void accum_atomic_kernel(
    const unsigned short* __restrict__ okeys, const float* __restrict__ ocontrib,
    const unsigned* __restrict__ gcur, unsigned cap,
    const uint2* __restrict__ ovf,
    float* __restrict__ y, int slices)
{
    __shared__ float acc[ROWS_PER_BIN];
    const int t   = threadIdx.x;
    const int bin = blockIdx.x / slices;
    const int sl  = blockIdx.x - bin * slices;

    float4 z = make_float4(0.f, 0.f, 0.f, 0.f);
    #pragma unroll
    for (int i = 0; i < ROWS_PER_BIN / (512 * 4); ++i)
        *reinterpret_cast<float4*>(&acc[(i * 512 + t) * 4]) = z;
    __syncthreads();

    unsigned count = gcur[bin * CUR_STRIDE];
    if (count > cap) count = cap;
    unsigned chunk = ((count + (unsigned)slices - 1u) / (unsigned)slices + 3u) & ~3u;
    unsigned lo = (unsigned)sl * chunk;
    unsigned hi = lo + chunk; if (hi > count) hi = count;

    const unsigned short* k = okeys    + (size_t)bin * cap;
    const float*          c = ocontrib + (size_t)bin * cap;

    unsigned i = lo + (unsigned)t * 4u;
    for (; i + 3u < hi; i += 2048u) {
        ushort4 k4 = *reinterpret_cast<const ushort4*>(k + i);
        float4  c4 = *reinterpret_cast<const float4*>(c + i);
        atomicAdd(&acc[k4.x], c4.x);
        atomicAdd(&acc[k4.y], c4.y);
        atomicAdd(&acc[k4.z], c4.z);
        atomicAdd(&acc[k4.w], c4.w);
    }
    for (; i < hi; ++i) atomicAdd(&acc[k[i]], c[i]);

    // Overflow entries (expected count: 0) folded in by slice 0 of each bin.
    if (sl == 0) {
        unsigned ovn = gcur[OVF_SLOT];
        if (ovn > OVF_CAP) ovn = OVF_CAP;
        for (unsigned j = (unsigned)t; j < ovn; j += 512u) {
            uint2 e = ovf[j];
            if ((int)(e.x >> ROW_SHIFT) == bin)
                atomicAdd(&acc[e.x & (ROWS_PER_BIN - 1)], __uint_as_float(e.y));
        }
    }
    __syncthreads();

    // Dump: coalesced atomic add into y. 64 consecutive floats per wave-instr;
    // each y cache line receives only `slices` updates total.
    float* yb = y + (size_t)bin * ROWS_PER_BIN;
    #pragma unroll
    for (int i2 = 0; i2 < ROWS_PER_BIN / (512 * 4); ++i2) {
        int l = (i2 * 512 + t) * 4;
        float4 v = *reinterpret_cast<const float4*>(&acc[l]);
        atomicAdd(&yb[l + 0], v.x);
        atomicAdd(&yb[l + 1], v.y);
        atomicAdd(&yb[l + 2], v.z);
        atomicAdd(&yb[l + 3], v.w);
    }
}

extern "C" void kernel_launch(void* const* d_in, const int* in_sizes, int n_in,
                              void* d_out, int out_size, void* d_ws, size_t ws_size,
                              hipStream_t stream) {
    const float* x    = (const float*)d_in[0];
    const float* vals = (const float*)d_in[1];
    const int*   rows = (const int*)d_in[2];
    const int*   cols = (const int*)d_in[3];
    float* y = (float*)d_out;

    const int nnz  = in_sizes[1];
    const int bins = (out_size + ROWS_PER_BIN - 1) / ROWS_PER_BIN;

    unsigned cap = (unsigned)(nnz / (bins > 0 ? bins : 1)) + 16384u;   // ~5.7 sigma slack
    cap = (cap + 3u) & ~3u;

    auto align256 = [](size_t v) { return (v + 255) & ~(size_t)255; };

    size_t off_contrib  = 0;
    size_t off_keys     = align256(off_contrib + (size_t)BINS * cap * 4);
    size_t off_gcur     = align256(off_keys + (size_t)BINS * cap * 2);
    size_t off_ovf      = align256(off_gcur + (size_t)(OVF_SLOT + CUR_STRIDE) * 4);
    size_t need         = align256(off_ovf + (size_t)OVF_CAP * 8);

    const bool ok = (bins == BINS) && (need <= ws_size) && (nnz > 0) &&
                    (out_size == BINS * ROWS_PER_BIN);

    if (!ok) {
        zero_out_kernel<<<(out_size + 255) / 256, 256, 0, stream>>>(y, out_size);
        spmv_coo_scatter<<<(nnz + 1023) / 1024, 256, 0, stream>>>(vals, rows, cols, x, y, nnz);
        return;
    }

    char* w = (char*)d_ws;
    float*          ocontrib = (float*)(w + off_contrib);
    unsigned short* okeys    = (unsigned short*)(w + off_keys);
    unsigned*       gcur     = (unsigned*)(w + off_gcur);
    uint2*          ovf      = (uint2*)(w + off_ovf);

    const int ncur = OVF_SLOT + 1;
    int initn = out_size > ncur ? out_size : ncur;
    init_kernel<<<(initn + 255) / 256, 256, 0, stream>>>(y, out_size, gcur, ncur);
    scatter_bucket_kernel<<<(nnz + ENT - 1) / ENT, 256, 0, stream>>>(
        rows, cols, vals, x, nnz, gcur, cap, okeys, ocontrib, ovf);
    accum_atomic_kernel<<<BINS * SLICES, 512, 0, stream>>>(
        okeys, ocontrib, gcur, cap, ovf, y, SLICES);
}

// Round 3
// 217.301 us; speedup vs baseline: 1.3859x; 1.3859x over previous
//
#include <hip/hip_runtime.h>

// y[rows[k]] += vals[k] * x[cols[k]]  — M=N=262144, NNZ=8388608, out 512x512 f32.
// Pipeline: init cursors -> block-local counting sort + coalesced scatter into
// 32 row-bins (R0 structure, batched gathers) -> per-bin-slice LDS accumulation
// with 4x-unrolled MLP-deep loads -> slice reduction.

#define BINS         32
#define ROW_SHIFT    13            // 8192 rows per bin
#define ROWS_PER_BIN 8192
#define ENT          4096          // entries per scatter block (16/thread)
#define CUR_STRIDE   32            // global cursor padding: 1 counter per 128B line
#define SLICES       16

typedef int   __attribute__((ext_vector_type(4))) i32x4;
typedef float __attribute__((ext_vector_type(4))) f32x4;

// ---------------- fallback path (known-correct) ----------------

__global__ __launch_bounds__(256) void zero_out_kernel(float* __restrict__ y, int n) {
    int i = blockIdx.x * blockDim.x + threadIdx.x;
    if (i < n) y[i] = 0.0f;
}

__global__ __launch_bounds__(256) void spmv_coo_scatter(
    const float* __restrict__ vals, const int* __restrict__ rows,
    const int* __restrict__ cols, const float* __restrict__ x,
    float* __restrict__ y, int nnz)
{
    int i = (blockIdx.x * blockDim.x + threadIdx.x) * 4;
    if (i + 3 < nnz) {
        float4 v = *reinterpret_cast<const float4*>(vals + i);
        int4   r = *reinterpret_cast<const int4*>(rows + i);
        int4   c = *reinterpret_cast<const int4*>(cols + i);
        atomicAdd(&y[r.x], v.x * x[c.x]);
        atomicAdd(&y[r.y], v.y * x[c.y]);
        atomicAdd(&y[r.z], v.z * x[c.z]);
        atomicAdd(&y[r.w], v.w * x[c.w]);
    } else {
        for (; i < nnz; ++i) atomicAdd(&y[rows[i]], vals[i] * x[cols[i]]);
    }
}

// ---------------- binned path ----------------

__global__ __launch_bounds__(256) void init_cursors(unsigned* __restrict__ gcur, int n) {
    int i = blockIdx.x * 256 + threadIdx.x;
    if (i < n) gcur[i] = 0u;
}

// Block-local counting sort + coalesced write of (key,contrib) into bin regions.
// R0 structure; gathers batched for MLP; shfl-based scan (no serial t==0 loop).
__global__ __launch_bounds__(256) void scatter2_kernel(
    const int*   __restrict__ rows, const int* __restrict__ cols,
    const float* __restrict__ vals, const float* __restrict__ x, int nnz,
    unsigned* __restrict__ gcur, unsigned cap,
    unsigned short* __restrict__ okeys, float* __restrict__ ocontrib)
{
    __shared__ unsigned cnt[BINS];
    __shared__ int      dstb[BINS];          // resv - lstart (signed index math)
    __shared__ unsigned cur2[BINS];
    __shared__ unsigned total_s;
    __shared__ unsigned short skey[ENT];
    __shared__ float          sval[ENT];
    __shared__ unsigned char  sbin[ENT];

    const int t = threadIdx.x;
    if (t < BINS) cnt[t] = 0u;
    __syncthreads();

    const int seg = blockIdx.x * ENT;

    int   rr[16];
    int   cc[16];
    float ff[16];

    // Pass A: load triplets. Keep all 16 col indices so the 16 x-gathers issue
    // as one independent batch (MLP), then multiply.
    if (seg + ENT <= nnz) {
        #pragma unroll
        for (int ch = 0; ch < 4; ++ch) {
            int base = seg + ch * 1024 + t * 4;
            i32x4 r4 = *reinterpret_cast<const i32x4*>(rows + base);
            i32x4 c4 = *reinterpret_cast<const i32x4*>(cols + base);
            f32x4 v4 = *reinterpret_cast<const f32x4*>(vals + base);
            rr[ch*4+0] = r4.x; cc[ch*4+0] = c4.x; ff[ch*4+0] = v4.x;
            rr[ch*4+1] = r4.y; cc[ch*4+1] = c4.y; ff[ch*4+1] = v4.y;
            rr[ch*4+2] = r4.z; cc[ch*4+2] = c4.z; ff[ch*4+2] = v4.z;
            rr[ch*4+3] = r4.w; cc[ch*4+3] = c4.w; ff[ch*4+3] = v4.w;
        }
        #pragma unroll
        for (int j = 0; j < 16; ++j) ff[j] *= x[cc[j]];
    } else {
        #pragma unroll
        for (int ch = 0; ch < 4; ++ch) {
            #pragma unroll
            for (int j = 0; j < 4; ++j) {
                int idx = seg + ch * 1024 + t * 4 + j;
                if (idx < nnz) { rr[ch*4+j] = rows[idx]; cc[ch*4+j] = cols[idx]; ff[ch*4+j] = vals[idx]; }
                else           { rr[ch*4+j] = -1; cc[ch*4+j] = 0; ff[ch*4+j] = 0.0f; }
            }
        }
        #pragma unroll
        for (int j = 0; j < 16; ++j) if (rr[j] >= 0) ff[j] *= x[cc[j]];
    }

    // Histogram (no-return LDS atomics).
    #pragma unroll
    for (int j = 0; j < 16; ++j)
        if (rr[j] >= 0) atomicAdd(&cnt[rr[j] >> ROW_SHIFT], 1u);
    __syncthreads();

    // Reserve global space per bin + exclusive scan of local counts (shfl, wave 0).
    if (t < BINS) {
        unsigned c = cnt[t];
        unsigned resv = atomicAdd(&gcur[t * CUR_STRIDE], c);
        unsigned v = c;
        #pragma unroll
        for (int d = 1; d < BINS; d <<= 1) {
            unsigned o = __shfl_up(v, d, 64);
            if (t >= d) v += o;
        }
        unsigned ls = v - c;
        cur2[t] = ls;
        dstb[t] = (int)resv - (int)ls;
        if (t == BINS - 1) total_s = v;
    }
    __syncthreads();

    // Pass B: place entries grouped by bin in LDS.
    #pragma unroll
    for (int j = 0; j < 16; ++j) {
        if (rr[j] >= 0) {
            int b = rr[j] >> ROW_SHIFT;
            unsigned p = atomicAdd(&cur2[b], 1u);
            skey[p] = (unsigned short)(rr[j] & (ROWS_PER_BIN - 1));
            sval[p] = ff[j];
            sbin[p] = (unsigned char)b;
        }
    }
    __syncthreads();

    // Copy-out: contiguous in LDS == contiguous in the bin's global region.
    const unsigned total = total_s;
    for (unsigned i = t; i < total; i += 256) {
        int b = sbin[i];
        unsigned off = (unsigned)(dstb[b] + (int)i);   // position within bin region
        if (off < cap) {
            size_t dst = (size_t)b * cap + off;
            okeys[dst]    = skey[i];
            ocontrib[dst] = sval[i];
        }
    }
}

// One block per (bin, slice): accumulate slice entries into LDS acc, dump partials.
// 512 threads; inner loop 4x-unrolled -> 8 independent loads in flight per thread.
__global__ __launch_bounds__(512) void accum2_kernel(
    const unsigned short* __restrict__ okeys, const float* __restrict__ ocontrib,
    const unsigned* __restrict__ gcur, unsigned cap,
    float* __restrict__ partials)
{
    __shared__ float acc[ROWS_PER_BIN];
    const int t   = threadIdx.x;
    const int bin = blockIdx.x / SLICES;
    const int sl  = blockIdx.x - bin * SLICES;

    float4 z = make_float4(0.f, 0.f, 0.f, 0.f);
    #pragma unroll
    for (int i = 0; i < ROWS_PER_BIN / (512 * 4); ++i)
        *reinterpret_cast<float4*>(&acc[(i * 512 + t) * 4]) = z;
    __syncthreads();

    unsigned count = gcur[bin * CUR_STRIDE];
    if (count > cap) count = cap;
    unsigned chunk = ((count + SLICES - 1u) / SLICES + 3u) & ~3u;
    unsigned lo = (unsigned)sl * chunk;
    unsigned hi = lo + chunk; if (hi > count) hi = count;

    const unsigned short* k = okeys    + (size_t)bin * cap;
    const float*          c = ocontrib + (size_t)bin * cap;

    unsigned i = lo + (unsigned)t * 4u;

    // 4x batch: 8 independent vector loads in flight before any LDS atomic.
    for (; i + 6147u < hi; i += 8192u) {
        ushort4 k0 = *reinterpret_cast<const ushort4*>(k + i);
        ushort4 k1 = *reinterpret_cast<const ushort4*>(k + i + 2048u);
        ushort4 k2 = *reinterpret_cast<const ushort4*>(k + i + 4096u);
        ushort4 k3 = *reinterpret_cast<const ushort4*>(k + i + 6144u);
        float4  c0 = *reinterpret_cast<const float4*>(c + i);
        float4  c1 = *reinterpret_cast<const float4*>(c + i + 2048u);
        float4  c2 = *reinterpret_cast<const float4*>(c + i + 4096u);
        float4  c3 = *reinterpret_cast<const float4*>(c + i + 6144u);
        atomicAdd(&acc[k0.x], c0.x); atomicAdd(&acc[k0.y], c0.y);
        atomicAdd(&acc[k0.z], c0.z); atomicAdd(&acc[k0.w], c0.w);
        atomicAdd(&acc[k1.x], c1.x); atomicAdd(&acc[k1.y], c1.y);
        atomicAdd(&acc[k1.z], c1.z); atomicAdd(&acc[k1.w], c1.w);
        atomicAdd(&acc[k2.x], c2.x); atomicAdd(&acc[k2.y], c2.y);
        atomicAdd(&acc[k2.z], c2.z); atomicAdd(&acc[k2.w], c2.w);
        atomicAdd(&acc[k3.x], c3.x); atomicAdd(&acc[k3.y], c3.y);
        atomicAdd(&acc[k3.z], c3.z); atomicAdd(&acc[k3.w], c3.w);
    }
    for (; i + 3u < hi; i += 2048u) {
        ushort4 k4 = *reinterpret_cast<const ushort4*>(k + i);
        float4  c4 = *reinterpret_cast<const float4*>(c + i);
        atomicAdd(&acc[k4.x], c4.x);
        atomicAdd(&acc[k4.y], c4.y);
        atomicAdd(&acc[k4.z], c4.z);
        atomicAdd(&acc[k4.w], c4.w);
    }
    for (; i < hi; ++i) atomicAdd(&acc[k[i]], c[i]);
    __syncthreads();

    float* p = partials + (size_t)blockIdx.x * ROWS_PER_BIN;
    #pragma unroll
    for (int i2 = 0; i2 < ROWS_PER_BIN / (512 * 4); ++i2) {
        int l = (i2 * 512 + t) * 4;
        *reinterpret_cast<float4*>(p + l) = *reinterpret_cast<const float4*>(&acc[l]);
    }
}

// Sum the SLICES partials per row, 4 rows per thread (float4).
__global__ __launch_bounds__(256) void reduce2_kernel(
    const float* __restrict__ partials, float* __restrict__ y, int out_size)
{
    int r0 = (blockIdx.x * 256 + threadIdx.x) * 4;
    if (r0 >= out_size) return;
    int bin = r0 >> ROW_SHIFT, local = r0 & (ROWS_PER_BIN - 1);
    const float* p = partials + ((size_t)bin * SLICES) * ROWS_PER_BIN + local;
    float4 s = make_float4(0.f, 0.f, 0.f, 0.f);
    #pragma unroll
    for (int j = 0; j < SLICES; ++j) {
        float4 v = *reinterpret_cast<const float4*>(p + (size_t)j * ROWS_PER_BIN);
        s.x += v.x; s.y += v.y; s.z += v.z; s.w += v.w;
    }
    *reinterpret_cast<float4*>(y + r0) = s;
}

extern "C" void kernel_launch(void* const* d_in, const int* in_sizes, int n_in,
                              void* d_out, int out_size, void* d_ws, size_t ws_size,
                              hipStream_t stream) {
    const float* x    = (const float*)d_in[0];
    const float* vals = (const float*)d_in[1];
    const int*   rows = (const int*)d_in[2];
    const int*   cols = (const int*)d_in[3];
    float* y = (float*)d_out;

    const int nnz  = in_sizes[1];
    const int bins = (out_size + ROWS_PER_BIN - 1) / ROWS_PER_BIN;

    unsigned cap = (unsigned)(nnz / (bins > 0 ? bins : 1)) + 16384u;   // ~32 sigma slack
    cap = (cap + 3u) & ~3u;

    auto align256 = [](size_t v) { return (v + 255) & ~(size_t)255; };

    size_t off_contrib  = 0;
    size_t off_keys     = align256(off_contrib + (size_t)BINS * cap * 4);
    size_t off_partials = align256(off_keys + (size_t)BINS * cap * 2);
    size_t off_gcur     = align256(off_partials + (size_t)BINS * SLICES * ROWS_PER_BIN * 4);
    size_t need         = align256(off_gcur + (size_t)BINS * CUR_STRIDE * 4);

    const bool ok = (bins == BINS) && (need <= ws_size) && (nnz > 0) &&
                    (out_size == BINS * ROWS_PER_BIN);

    if (!ok) {
        zero_out_kernel<<<(out_size + 255) / 256, 256, 0, stream>>>(y, out_size);
        spmv_coo_scatter<<<(nnz + 1023) / 1024, 256, 0, stream>>>(vals, rows, cols, x, y, nnz);
        return;
    }

    char* w = (char*)d_ws;
    float*          ocontrib = (float*)(w + off_contrib);
    unsigned short* okeys    = (unsigned short*)(w + off_keys);
    float*          partials = (float*)(w + off_partials);
    unsigned*       gcur     = (unsigned*)(w + off_gcur);

    const int ncur = BINS * CUR_STRIDE;
    init_cursors<<<(ncur + 255) / 256, 256, 0, stream>>>(gcur, ncur);
    scatter2_kernel<<<(nnz + ENT - 1) / ENT, 256, 0, stream>>>(
        rows, cols, vals, x, nnz, gcur, cap, okeys, ocontrib);
    accum2_kernel<<<BINS * SLICES, 512, 0, stream>>>(okeys, ocontrib, gcur, cap, partials);
    reduce2_kernel<<<(out_size / 4 + 255) / 256, 256, 0, stream>>>(partials, y, out_size);
}